// Round 1
// baseline (8885.952 us; speedup 1.0000x reference)
//
#include <hip/hip_runtime.h>

#define H 128

// ---- float <-> monotone-unsigned encoding for atomicMax on floats ----
__device__ __forceinline__ unsigned fenc(float x) {
  unsigned b = __float_as_uint(x);
  return (b & 0x80000000u) ? ~b : (b | 0x80000000u);
}
__device__ __forceinline__ float fdec(unsigned e) {
  return (e & 0x80000000u) ? __uint_as_float(e & 0x7fffffffu)
                           : __uint_as_float(~e);
}

// ---- degree count: cnt[dst[e]] += 1 ----
__global__ void deg_kernel(const int* __restrict__ dst, int* __restrict__ cnt, int ne) {
  int e = blockIdx.x * blockDim.x + threadIdx.x;
  if (e < ne) atomicAdd(&cnt[dst[e]], 1);
}

// ---- dinv[i] = rsqrt(cnt[i] + 1)  (self-loop) ----
__global__ void dinv_kernel(const int* __restrict__ cnt, float* __restrict__ dinv, int n) {
  int i = blockIdx.x * blockDim.x + threadIdx.x;
  if (i < n) dinv[i] = rsqrtf((float)(cnt[i] + 1));
}

// ---- out[r][c] = (X @ W)[r][c] * dinv[r]   (64 rows x 128 cols per block) ----
__global__ __launch_bounds__(256) void gemm_scale(
    const float* __restrict__ X, const float* __restrict__ W,
    const float* __restrict__ dinv, float* __restrict__ out, int n) {
  __shared__ float sX[64][8];   // 64 rows x 8 k
  __shared__ float sW[8][H];    // 8 k x 128 cols
  int tid = threadIdx.x;
  int row0 = blockIdx.x * 64;
  int rg = tid >> 5;            // 0..7 -> rows rg*8 .. rg*8+7
  int cg = (tid & 31) << 2;     // col base 0,4,...,124

  float acc[8][4];
#pragma unroll
  for (int r = 0; r < 8; ++r) { acc[r][0]=0.f; acc[r][1]=0.f; acc[r][2]=0.f; acc[r][3]=0.f; }

  for (int k0 = 0; k0 < H; k0 += 8) {
    if (tid < 128) {
      int rr = tid >> 1;
      int r  = row0 + rr;
      int kk = (tid & 1) << 2;
      float4 v = make_float4(0.f, 0.f, 0.f, 0.f);
      if (r < n) v = *(const float4*)(X + (size_t)r * H + k0 + kk);
      *(float4*)&sX[rr][kk] = v;
    }
    {
      int kk = tid >> 5;
      int c  = (tid & 31) << 2;
      *(float4*)&sW[kk][c] = *(const float4*)(W + (size_t)(k0 + kk) * H + c);
    }
    __syncthreads();
#pragma unroll
    for (int kk = 0; kk < 8; ++kk) {
      float4 wv = *(float4*)&sW[kk][cg];
#pragma unroll
      for (int r = 0; r < 8; ++r) {
        float xv = sX[rg * 8 + r][kk];
        acc[r][0] = fmaf(xv, wv.x, acc[r][0]);
        acc[r][1] = fmaf(xv, wv.y, acc[r][1]);
        acc[r][2] = fmaf(xv, wv.z, acc[r][2]);
        acc[r][3] = fmaf(xv, wv.w, acc[r][3]);
      }
    }
    __syncthreads();
  }
#pragma unroll
  for (int r = 0; r < 8; ++r) {
    int row = row0 + rg * 8 + r;
    if (row < n) {
      float dv = dinv[row];
      float4 o;
      o.x = acc[r][0] * dv; o.y = acc[r][1] * dv;
      o.z = acc[r][2] * dv; o.w = acc[r][3] * dv;
      *(float4*)(out + (size_t)row * H + cg) = o;
    }
  }
}

// ---- scatter: agg[dst[e]][:] += hs[src[e]][:]   (32 lanes/edge, float4/lane) ----
__global__ __launch_bounds__(256) void scatter_add(
    const int* __restrict__ src, const int* __restrict__ dst,
    const float* __restrict__ hs, float* __restrict__ agg, int ne) {
  int e = blockIdx.x * 8 + (threadIdx.x >> 5);
  if (e >= ne) return;
  int lane = (threadIdx.x & 31) << 2;
  int s = src[e], d = dst[e];
  float4 v = *(const float4*)(hs + (size_t)s * H + lane);
  float* p = agg + (size_t)d * H + lane;
  unsafeAtomicAdd(p + 0, v.x);
  unsafeAtomicAdd(p + 1, v.y);
  unsafeAtomicAdd(p + 2, v.z);
  unsafeAtomicAdd(p + 3, v.w);
}

// ---- finalize: buf = maybe_relu(dinv[r]*buf + b[c]) ----
template <bool RELU>
__global__ void finalize_kernel(float* __restrict__ buf, const float* __restrict__ dinv,
                                const float* __restrict__ b, int n) {
  int t = blockIdx.x * blockDim.x + threadIdx.x;   // over n*32 float4-slots
  int row = t >> 5;
  int c = (t & 31) << 2;
  if (row >= n) return;
  float dv = dinv[row];
  float4 v = *(float4*)(buf + (size_t)row * H + c);
  float4 bb = *(const float4*)(b + c);
  v.x = fmaf(v.x, dv, bb.x); v.y = fmaf(v.y, dv, bb.y);
  v.z = fmaf(v.z, dv, bb.z); v.w = fmaf(v.w, dv, bb.w);
  if (RELU) {
    v.x = fmaxf(v.x, 0.f); v.y = fmaxf(v.y, 0.f);
    v.z = fmaxf(v.z, 0.f); v.w = fmaxf(v.w, 0.f);
  }
  *(float4*)(buf + (size_t)row * H + c) = v;
}

// ---- pooling: per-graph sum (f32 atomics) + max (encoded u32 atomicMax) + count ----
__global__ __launch_bounds__(256) void pool_kernel(
    const float* __restrict__ h, const int* __restrict__ batch,
    float* __restrict__ sums, unsigned* __restrict__ maxenc,
    int* __restrict__ cnt, int n) {
  int node = blockIdx.x * 8 + (threadIdx.x >> 5);
  if (node >= n) return;
  int lane = (threadIdx.x & 31) << 2;
  int g = batch[node];
  float4 v = *(const float4*)(h + (size_t)node * H + lane);
  float* sp = sums + (size_t)g * H + lane;
  unsafeAtomicAdd(sp + 0, v.x);
  unsafeAtomicAdd(sp + 1, v.y);
  unsafeAtomicAdd(sp + 2, v.z);
  unsafeAtomicAdd(sp + 3, v.w);
  unsigned* mp = maxenc + (size_t)g * H + lane;
  atomicMax(mp + 0, fenc(v.x));
  atomicMax(mp + 1, fenc(v.y));
  atomicMax(mp + 2, fenc(v.z));
  atomicMax(mp + 3, fenc(v.w));
  if ((threadIdx.x & 31) == 0) atomicAdd(&cnt[g], 1);
}

// ---- classifier: one block per graph; g=[mean||max]; relu(g@Wc1+bc1)@Wc2+bc2 ----
__global__ __launch_bounds__(128) void classify_kernel(
    const float* __restrict__ sums, const unsigned* __restrict__ maxenc,
    const int* __restrict__ cnt,
    const float* __restrict__ Wc1, const float* __restrict__ bc1,
    const float* __restrict__ Wc2, const float* __restrict__ bc2,
    float* __restrict__ out) {
  __shared__ float gv[2 * H];
  __shared__ float hid[H];
  int gid = blockIdx.x;
  int t = threadIdx.x;  // 0..127
  float c = (float)cnt[gid];
  float inv = 1.0f / fmaxf(c, 1.0f);
  gv[t] = sums[(size_t)gid * H + t] * inv;
  unsigned e = maxenc[(size_t)gid * H + t];
  gv[H + t] = (e == 0u) ? 0.0f : fdec(e);   // sentinel 0 => empty segment => 0
  __syncthreads();
  float acc = 0.f;
#pragma unroll 8
  for (int k = 0; k < 2 * H; ++k) acc = fmaf(gv[k], Wc1[(size_t)k * H + t], acc);
  hid[t] = fmaxf(acc + bc1[t], 0.f);
  __syncthreads();
  if (t < 10) {
    float a2 = 0.f;
    for (int j = 0; j < H; ++j) a2 = fmaf(hid[j], Wc2[(size_t)j * 10 + t], a2);
    out[(size_t)gid * 10 + t] = a2 + bc2[t];
  }
}

extern "C" void kernel_launch(void* const* d_in, const int* in_sizes, int n_in,
                              void* d_out, int out_size, void* d_ws, size_t ws_size,
                              hipStream_t stream) {
  const float* x    = (const float*)d_in[0];
  const int* ei     = (const int*)d_in[1];
  const int* batch  = (const int*)d_in[2];
  const float* W1   = (const float*)d_in[3];
  const float* b1   = (const float*)d_in[4];
  const float* W2   = (const float*)d_in[5];
  const float* b2   = (const float*)d_in[6];
  const float* W3   = (const float*)d_in[7];
  const float* b3   = (const float*)d_in[8];
  const float* Wc1  = (const float*)d_in[9];
  const float* bc1  = (const float*)d_in[10];
  const float* Wc2  = (const float*)d_in[11];
  const float* bc2  = (const float*)d_in[12];
  float* out = (float*)d_out;

  const int n  = in_sizes[2];        // 100000 nodes
  const int ne = in_sizes[1] / 2;    // 1600000 edges
  const int G  = 512;
  const size_t NF = (size_t)n * H;

  const int* src = ei;
  const int* dst = ei + ne;

  // ---- workspace layout ----
  float* A = (float*)d_ws;                 // hs buffer  [n,128]
  float* B = A + NF;                       // agg/output [n,128]
  char* p = (char*)(B + NF);
  int*      deg_cnt = (int*)p;       p += (size_t)n * 4;
  float*    sums    = (float*)p;     p += (size_t)G * H * 4;
  unsigned* maxenc  = (unsigned*)p;  p += (size_t)G * H * 4;
  int*      gcnt    = (int*)p;       p += (size_t)G * 4;
  float*    dinv    = (float*)p;     p += (size_t)n * 4;

  // zero: deg_cnt + sums + maxenc + gcnt (contiguous)
  size_t zero_bytes = (size_t)n * 4 + (size_t)G * H * 4 * 2 + (size_t)G * 4;
  hipMemsetAsync(deg_cnt, 0, zero_bytes, stream);

  // degree -> dinv (shared across all 3 layers)
  deg_kernel<<<(ne + 255) / 256, 256, 0, stream>>>(dst, deg_cnt, ne);
  dinv_kernel<<<(n + 255) / 256, 256, 0, stream>>>(deg_cnt, dinv, n);

  const int gemm_grid  = (n + 63) / 64;
  const int edge_grid  = (ne + 7) / 8;
  const int fin_grid   = ((n * 32) + 255) / 256;
  const size_t nf_bytes = NF * sizeof(float);

  // ---- layer 1 ----
  gemm_scale<<<gemm_grid, 256, 0, stream>>>(x, W1, dinv, A, n);
  hipMemcpyAsync(B, A, nf_bytes, hipMemcpyDeviceToDevice, stream);  // self-loop seed
  scatter_add<<<edge_grid, 256, 0, stream>>>(src, dst, A, B, ne);
  finalize_kernel<true><<<fin_grid, 256, 0, stream>>>(B, dinv, b1, n);

  // ---- layer 2 ----
  gemm_scale<<<gemm_grid, 256, 0, stream>>>(B, W2, dinv, A, n);
  hipMemcpyAsync(B, A, nf_bytes, hipMemcpyDeviceToDevice, stream);
  scatter_add<<<edge_grid, 256, 0, stream>>>(src, dst, A, B, ne);
  finalize_kernel<true><<<fin_grid, 256, 0, stream>>>(B, dinv, b2, n);

  // ---- layer 3 (no relu) ----
  gemm_scale<<<gemm_grid, 256, 0, stream>>>(B, W3, dinv, A, n);
  hipMemcpyAsync(B, A, nf_bytes, hipMemcpyDeviceToDevice, stream);
  scatter_add<<<edge_grid, 256, 0, stream>>>(src, dst, A, B, ne);
  finalize_kernel<false><<<fin_grid, 256, 0, stream>>>(B, dinv, b3, n);

  // ---- pooling + classifier ----
  pool_kernel<<<(n + 7) / 8, 256, 0, stream>>>(B, batch, sums, maxenc, gcnt, n);
  classify_kernel<<<G, 128, 0, stream>>>(sums, maxenc, gcnt, Wc1, bc1, Wc2, bc2, out);
}

// Round 2
// 1283.380 us; speedup vs baseline: 6.9239x; 6.9239x over previous
//
#include <hip/hip_runtime.h>

#define H 128

// ---- float <-> monotone-unsigned encoding for atomicMax on floats ----
__device__ __forceinline__ unsigned fenc(float x) {
  unsigned b = __float_as_uint(x);
  return (b & 0x80000000u) ? ~b : (b | 0x80000000u);
}
__device__ __forceinline__ float fdec(unsigned e) {
  return (e & 0x80000000u) ? __uint_as_float(e & 0x7fffffffu)
                           : __uint_as_float(~e);
}

// ---- degree count: cnt[dst[e]] += 1 ----
__global__ void deg_kernel(const int* __restrict__ dst, int* __restrict__ cnt, int ne) {
  int e = blockIdx.x * blockDim.x + threadIdx.x;
  if (e < ne) atomicAdd(&cnt[dst[e]], 1);
}

// ---- dinv[i] = rsqrt(cnt[i] + 1)  (self-loop) ----
__global__ void dinv_kernel(const int* __restrict__ cnt, float* __restrict__ dinv, int n) {
  int i = blockIdx.x * blockDim.x + threadIdx.x;
  if (i < n) dinv[i] = rsqrtf((float)(cnt[i] + 1));
}

// ---- exclusive scan, stage 1: 1024 elems/block ----
__global__ __launch_bounds__(256) void scan1(const int* __restrict__ in,
                                             int* __restrict__ out,
                                             int* __restrict__ partials, int n) {
  __shared__ int sdata[256];
  int base = blockIdx.x * 1024;
  int t = threadIdx.x;
  int v[4];
  int sum = 0;
#pragma unroll
  for (int j = 0; j < 4; ++j) {
    int idx = base + t * 4 + j;
    v[j] = (idx < n) ? in[idx] : 0;
    sum += v[j];
  }
  sdata[t] = sum;
  __syncthreads();
  for (int off = 1; off < 256; off <<= 1) {
    int y = (t >= off) ? sdata[t - off] : 0;
    __syncthreads();
    sdata[t] += y;
    __syncthreads();
  }
  int excl = sdata[t] - sum;
  int run = excl;
#pragma unroll
  for (int j = 0; j < 4; ++j) {
    int idx = base + t * 4 + j;
    if (idx < n) out[idx] = run;
    run += v[j];
  }
  if (t == 255) partials[blockIdx.x] = sdata[255];
}

// ---- scan stage 2: single block scans the block totals (nb <= 256) ----
__global__ __launch_bounds__(256) void scan2(int* __restrict__ partials, int nb) {
  __shared__ int sdata[256];
  int t = threadIdx.x;
  int v = (t < nb) ? partials[t] : 0;
  sdata[t] = v;
  __syncthreads();
  for (int off = 1; off < 256; off <<= 1) {
    int y = (t >= off) ? sdata[t - off] : 0;
    __syncthreads();
    sdata[t] += y;
    __syncthreads();
  }
  if (t < nb) partials[t] = sdata[t] - v;
}

// ---- scan stage 3: add block offsets; set row_start[n] = ne ----
__global__ void scan3(int* __restrict__ out, const int* __restrict__ partials,
                      int n, int ne) {
  int i = blockIdx.x * blockDim.x + threadIdx.x;
  if (i < n) out[i] += partials[i >> 10];
  if (i == 0) out[n] = ne;
}

// ---- CSR fill: csr_src[cursor[dst[e]]++] = src[e] ----
__global__ void csr_fill(const int* __restrict__ src, const int* __restrict__ dst,
                         int* __restrict__ cursor, int* __restrict__ csr_src, int ne) {
  int e = blockIdx.x * blockDim.x + threadIdx.x;
  if (e < ne) {
    int p = atomicAdd(&cursor[dst[e]], 1);
    csr_src[p] = src[e];
  }
}

// ---- out[r][c] = (X @ W)[r][c] * dinv[r]   (64 rows x 128 cols per block) ----
__global__ __launch_bounds__(256) void gemm_scale(
    const float* __restrict__ X, const float* __restrict__ W,
    const float* __restrict__ dinv, float* __restrict__ out, int n) {
  __shared__ float sX[64][8];
  __shared__ float sW[8][H];
  int tid = threadIdx.x;
  int row0 = blockIdx.x * 64;
  int rg = tid >> 5;
  int cg = (tid & 31) << 2;

  float acc[8][4];
#pragma unroll
  for (int r = 0; r < 8; ++r) { acc[r][0]=0.f; acc[r][1]=0.f; acc[r][2]=0.f; acc[r][3]=0.f; }

  for (int k0 = 0; k0 < H; k0 += 8) {
    if (tid < 128) {
      int rr = tid >> 1;
      int r  = row0 + rr;
      int kk = (tid & 1) << 2;
      float4 v = make_float4(0.f, 0.f, 0.f, 0.f);
      if (r < n) v = *(const float4*)(X + (size_t)r * H + k0 + kk);
      *(float4*)&sX[rr][kk] = v;
    }
    {
      int kk = tid >> 5;
      int c  = (tid & 31) << 2;
      *(float4*)&sW[kk][c] = *(const float4*)(W + (size_t)(k0 + kk) * H + c);
    }
    __syncthreads();
#pragma unroll
    for (int kk = 0; kk < 8; ++kk) {
      float4 wv = *(float4*)&sW[kk][cg];
#pragma unroll
      for (int r = 0; r < 8; ++r) {
        float xv = sX[rg * 8 + r][kk];
        acc[r][0] = fmaf(xv, wv.x, acc[r][0]);
        acc[r][1] = fmaf(xv, wv.y, acc[r][1]);
        acc[r][2] = fmaf(xv, wv.z, acc[r][2]);
        acc[r][3] = fmaf(xv, wv.w, acc[r][3]);
      }
    }
    __syncthreads();
  }
#pragma unroll
  for (int r = 0; r < 8; ++r) {
    int row = row0 + rg * 8 + r;
    if (row < n) {
      float dv = dinv[row];
      float4 o;
      o.x = acc[r][0] * dv; o.y = acc[r][1] * dv;
      o.z = acc[r][2] * dv; o.w = acc[r][3] * dv;
      *(float4*)(out + (size_t)row * H + cg) = o;
    }
  }
}

// ---- aggregate (gather): out[i] = maybe_relu(dinv[i]*(sum_{e:dst=i} hs[src] + hs[i]) + b) ----
template <bool RELU>
__global__ __launch_bounds__(256) void aggregate(
    const float* __restrict__ hs, const int* __restrict__ row_start,
    const int* __restrict__ csr_src, const float* __restrict__ dinv,
    const float* __restrict__ b, float* __restrict__ out, int n) {
  int node = blockIdx.x * 8 + (threadIdx.x >> 5);
  if (node >= n) return;
  int c = (threadIdx.x & 31) << 2;
  int beg = row_start[node];
  int end = row_start[node + 1];

  float4 acc = *(const float4*)(hs + (size_t)node * H + c);  // self-loop term
  int k = beg;
  for (; k + 3 < end; k += 4) {
    int s0 = csr_src[k + 0];
    int s1 = csr_src[k + 1];
    int s2 = csr_src[k + 2];
    int s3 = csr_src[k + 3];
    float4 v0 = *(const float4*)(hs + (size_t)s0 * H + c);
    float4 v1 = *(const float4*)(hs + (size_t)s1 * H + c);
    float4 v2 = *(const float4*)(hs + (size_t)s2 * H + c);
    float4 v3 = *(const float4*)(hs + (size_t)s3 * H + c);
    acc.x += (v0.x + v1.x) + (v2.x + v3.x);
    acc.y += (v0.y + v1.y) + (v2.y + v3.y);
    acc.z += (v0.z + v1.z) + (v2.z + v3.z);
    acc.w += (v0.w + v1.w) + (v2.w + v3.w);
  }
  for (; k < end; ++k) {
    int s = csr_src[k];
    float4 v = *(const float4*)(hs + (size_t)s * H + c);
    acc.x += v.x; acc.y += v.y; acc.z += v.z; acc.w += v.w;
  }

  float dv = dinv[node];
  float4 bb = *(const float4*)(b + c);
  float4 o;
  o.x = fmaf(acc.x, dv, bb.x);
  o.y = fmaf(acc.y, dv, bb.y);
  o.z = fmaf(acc.z, dv, bb.z);
  o.w = fmaf(acc.w, dv, bb.w);
  if (RELU) {
    o.x = fmaxf(o.x, 0.f); o.y = fmaxf(o.y, 0.f);
    o.z = fmaxf(o.z, 0.f); o.w = fmaxf(o.w, 0.f);
  }
  *(float4*)(out + (size_t)node * H + c) = o;
}

// ---- pooling: per-graph sum (f32 atomics) + max (encoded u32 atomicMax) + count ----
__global__ __launch_bounds__(256) void pool_kernel(
    const float* __restrict__ h, const int* __restrict__ batch,
    float* __restrict__ sums, unsigned* __restrict__ maxenc,
    int* __restrict__ cnt, int n) {
  int node = blockIdx.x * 8 + (threadIdx.x >> 5);
  if (node >= n) return;
  int lane = (threadIdx.x & 31) << 2;
  int g = batch[node];
  float4 v = *(const float4*)(h + (size_t)node * H + lane);
  float* sp = sums + (size_t)g * H + lane;
  unsafeAtomicAdd(sp + 0, v.x);
  unsafeAtomicAdd(sp + 1, v.y);
  unsafeAtomicAdd(sp + 2, v.z);
  unsafeAtomicAdd(sp + 3, v.w);
  unsigned* mp = maxenc + (size_t)g * H + lane;
  atomicMax(mp + 0, fenc(v.x));
  atomicMax(mp + 1, fenc(v.y));
  atomicMax(mp + 2, fenc(v.z));
  atomicMax(mp + 3, fenc(v.w));
  if ((threadIdx.x & 31) == 0) atomicAdd(&cnt[g], 1);
}

// ---- classifier: one block per graph ----
__global__ __launch_bounds__(128) void classify_kernel(
    const float* __restrict__ sums, const unsigned* __restrict__ maxenc,
    const int* __restrict__ cnt,
    const float* __restrict__ Wc1, const float* __restrict__ bc1,
    const float* __restrict__ Wc2, const float* __restrict__ bc2,
    float* __restrict__ out) {
  __shared__ float gv[2 * H];
  __shared__ float hid[H];
  int gid = blockIdx.x;
  int t = threadIdx.x;
  float c = (float)cnt[gid];
  float inv = 1.0f / fmaxf(c, 1.0f);
  gv[t] = sums[(size_t)gid * H + t] * inv;
  unsigned e = maxenc[(size_t)gid * H + t];
  gv[H + t] = (e == 0u) ? 0.0f : fdec(e);
  __syncthreads();
  float acc = 0.f;
#pragma unroll 8
  for (int k = 0; k < 2 * H; ++k) acc = fmaf(gv[k], Wc1[(size_t)k * H + t], acc);
  hid[t] = fmaxf(acc + bc1[t], 0.f);
  __syncthreads();
  if (t < 10) {
    float a2 = 0.f;
    for (int j = 0; j < H; ++j) a2 = fmaf(hid[j], Wc2[(size_t)j * 10 + t], a2);
    out[(size_t)gid * 10 + t] = a2 + bc2[t];
  }
}

extern "C" void kernel_launch(void* const* d_in, const int* in_sizes, int n_in,
                              void* d_out, int out_size, void* d_ws, size_t ws_size,
                              hipStream_t stream) {
  const float* x    = (const float*)d_in[0];
  const int* ei     = (const int*)d_in[1];
  const int* batch  = (const int*)d_in[2];
  const float* W1   = (const float*)d_in[3];
  const float* b1   = (const float*)d_in[4];
  const float* W2   = (const float*)d_in[5];
  const float* b2   = (const float*)d_in[6];
  const float* W3   = (const float*)d_in[7];
  const float* b3   = (const float*)d_in[8];
  const float* Wc1  = (const float*)d_in[9];
  const float* bc1  = (const float*)d_in[10];
  const float* Wc2  = (const float*)d_in[11];
  const float* bc2  = (const float*)d_in[12];
  float* out = (float*)d_out;

  const int n  = in_sizes[2];        // 100000 nodes
  const int ne = in_sizes[1] / 2;    // 1600000 edges
  const int G  = 512;
  const size_t NF = (size_t)n * H;

  const int* src = ei;
  const int* dst = ei + ne;

  // ---- workspace layout ----
  float* A = (float*)d_ws;                 // hs buffer  [n,128]
  float* B = A + NF;                       // agg/output [n,128]
  char* p = (char*)(B + NF);
  int*      deg_cnt  = (int*)p;       p += (size_t)n * 4;          // zeroed
  float*    sums     = (float*)p;     p += (size_t)G * H * 4;      // zeroed
  unsigned* maxenc   = (unsigned*)p;  p += (size_t)G * H * 4;      // zeroed
  int*      gcnt     = (int*)p;       p += (size_t)G * 4;          // zeroed
  float*    dinv     = (float*)p;     p += (size_t)n * 4;
  int*      row_start= (int*)p;       p += (size_t)(n + 1) * 4;
  int*      cursor   = (int*)p;       p += (size_t)n * 4;
  int*      partials = (int*)p;       p += (size_t)256 * 4;
  int*      csr_src  = (int*)p;       p += (size_t)ne * 4;

  size_t zero_bytes = (size_t)n * 4 + (size_t)G * H * 4 * 2 + (size_t)G * 4;
  hipMemsetAsync(deg_cnt, 0, zero_bytes, stream);

  // ---- CSR build (once, reused by all 3 layers) ----
  deg_kernel<<<(ne + 255) / 256, 256, 0, stream>>>(dst, deg_cnt, ne);
  dinv_kernel<<<(n + 255) / 256, 256, 0, stream>>>(deg_cnt, dinv, n);
  int nb = (n + 1023) / 1024;   // 98 blocks for n=100000 (<=256 required)
  scan1<<<nb, 256, 0, stream>>>(deg_cnt, row_start, partials, n);
  scan2<<<1, 256, 0, stream>>>(partials, nb);
  scan3<<<(n + 255) / 256, 256, 0, stream>>>(row_start, partials, n, ne);
  hipMemcpyAsync(cursor, row_start, (size_t)n * 4, hipMemcpyDeviceToDevice, stream);
  csr_fill<<<(ne + 255) / 256, 256, 0, stream>>>(src, dst, cursor, csr_src, ne);

  const int gemm_grid = (n + 63) / 64;
  const int node_grid = (n + 7) / 8;

  // ---- layer 1 ----
  gemm_scale<<<gemm_grid, 256, 0, stream>>>(x, W1, dinv, A, n);
  aggregate<true><<<node_grid, 256, 0, stream>>>(A, row_start, csr_src, dinv, b1, B, n);

  // ---- layer 2 ----
  gemm_scale<<<gemm_grid, 256, 0, stream>>>(B, W2, dinv, A, n);
  aggregate<true><<<node_grid, 256, 0, stream>>>(A, row_start, csr_src, dinv, b2, B, n);

  // ---- layer 3 (no relu) ----
  gemm_scale<<<gemm_grid, 256, 0, stream>>>(B, W3, dinv, A, n);
  aggregate<false><<<node_grid, 256, 0, stream>>>(A, row_start, csr_src, dinv, b3, B, n);

  // ---- pooling + classifier ----
  pool_kernel<<<node_grid, 256, 0, stream>>>(B, batch, sums, maxenc, gcnt, n);
  classify_kernel<<<G, 128, 0, stream>>>(sums, maxenc, gcnt, Wc1, bc1, Wc2, bc2, out);
}

// Round 3
// 849.121 us; speedup vs baseline: 10.4649x; 1.5114x over previous
//
#include <hip/hip_runtime.h>

#define H 128

// ---- degree count: cnt[dst[e]] += 1 ----
__global__ void deg_kernel(const int* __restrict__ dst, int* __restrict__ cnt, int ne) {
  int e = blockIdx.x * blockDim.x + threadIdx.x;
  if (e < ne) atomicAdd(&cnt[dst[e]], 1);
}

// ---- dinv[i] = rsqrt(cnt[i] + 1)  (self-loop) ----
__global__ void dinv_kernel(const int* __restrict__ cnt, float* __restrict__ dinv, int n) {
  int i = blockIdx.x * blockDim.x + threadIdx.x;
  if (i < n) dinv[i] = rsqrtf((float)(cnt[i] + 1));
}

// ---- exclusive scan, stage 1: 1024 elems/block ----
__global__ __launch_bounds__(256) void scan1(const int* __restrict__ in,
                                             int* __restrict__ out,
                                             int* __restrict__ partials, int n) {
  __shared__ int sdata[256];
  int base = blockIdx.x * 1024;
  int t = threadIdx.x;
  int v[4];
  int sum = 0;
#pragma unroll
  for (int j = 0; j < 4; ++j) {
    int idx = base + t * 4 + j;
    v[j] = (idx < n) ? in[idx] : 0;
    sum += v[j];
  }
  sdata[t] = sum;
  __syncthreads();
  for (int off = 1; off < 256; off <<= 1) {
    int y = (t >= off) ? sdata[t - off] : 0;
    __syncthreads();
    sdata[t] += y;
    __syncthreads();
  }
  int excl = sdata[t] - sum;
  int run = excl;
#pragma unroll
  for (int j = 0; j < 4; ++j) {
    int idx = base + t * 4 + j;
    if (idx < n) out[idx] = run;
    run += v[j];
  }
  if (t == 255) partials[blockIdx.x] = sdata[255];
}

// ---- scan stage 2: single block scans block totals (nb <= 256) ----
__global__ __launch_bounds__(256) void scan2(int* __restrict__ partials, int nb) {
  __shared__ int sdata[256];
  int t = threadIdx.x;
  int v = (t < nb) ? partials[t] : 0;
  sdata[t] = v;
  __syncthreads();
  for (int off = 1; off < 256; off <<= 1) {
    int y = (t >= off) ? sdata[t - off] : 0;
    __syncthreads();
    sdata[t] += y;
    __syncthreads();
  }
  if (t < nb) partials[t] = sdata[t] - v;
}

// ---- scan stage 3: add block offsets; set row_start[n] = ne ----
__global__ void scan3(int* __restrict__ out, const int* __restrict__ partials,
                      int n, int ne) {
  int i = blockIdx.x * blockDim.x + threadIdx.x;
  if (i < n) out[i] += partials[i >> 10];
  if (i == 0) out[n] = ne;
}

// ---- CSR fill: csr_src[cursor[dst[e]]++] = src[e] ----
__global__ void csr_fill(const int* __restrict__ src, const int* __restrict__ dst,
                         int* __restrict__ cursor, int* __restrict__ csr_src, int ne) {
  int e = blockIdx.x * blockDim.x + threadIdx.x;
  if (e < ne) {
    int p = atomicAdd(&cursor[dst[e]], 1);
    csr_src[p] = src[e];
  }
}

// ---- graph boundaries from sorted batch: g_start[g] = first node of graph g ----
__global__ void gstart_kernel(const int* __restrict__ batch, int* __restrict__ g_start,
                              int n, int G) {
  int i = blockIdx.x * blockDim.x + threadIdx.x;
  if (i >= n) return;
  int b = batch[i];
  int prev = (i == 0) ? -1 : batch[i - 1];
  for (int g = prev + 1; g <= b; ++g) g_start[g] = i;
  if (i == n - 1) {
    for (int g = b + 1; g <= G; ++g) g_start[g] = n;
  }
}

// ---- out[r][c] = (X @ W)[r][c] * dinv[r]   (64 rows x 128 cols per block) ----
__global__ __launch_bounds__(256) void gemm_scale(
    const float* __restrict__ X, const float* __restrict__ W,
    const float* __restrict__ dinv, float* __restrict__ out, int n) {
  __shared__ float sX[64][8];
  __shared__ float sW[8][H];
  int tid = threadIdx.x;
  int row0 = blockIdx.x * 64;
  int rg = tid >> 5;
  int cg = (tid & 31) << 2;

  float acc[8][4];
#pragma unroll
  for (int r = 0; r < 8; ++r) { acc[r][0]=0.f; acc[r][1]=0.f; acc[r][2]=0.f; acc[r][3]=0.f; }

  for (int k0 = 0; k0 < H; k0 += 8) {
    if (tid < 128) {
      int rr = tid >> 1;
      int r  = row0 + rr;
      int kk = (tid & 1) << 2;
      float4 v = make_float4(0.f, 0.f, 0.f, 0.f);
      if (r < n) v = *(const float4*)(X + (size_t)r * H + k0 + kk);
      *(float4*)&sX[rr][kk] = v;
    }
    {
      int kk = tid >> 5;
      int c  = (tid & 31) << 2;
      *(float4*)&sW[kk][c] = *(const float4*)(W + (size_t)(k0 + kk) * H + c);
    }
    __syncthreads();
#pragma unroll
    for (int kk = 0; kk < 8; ++kk) {
      float4 wv = *(float4*)&sW[kk][cg];
#pragma unroll
      for (int r = 0; r < 8; ++r) {
        float xv = sX[rg * 8 + r][kk];
        acc[r][0] = fmaf(xv, wv.x, acc[r][0]);
        acc[r][1] = fmaf(xv, wv.y, acc[r][1]);
        acc[r][2] = fmaf(xv, wv.z, acc[r][2]);
        acc[r][3] = fmaf(xv, wv.w, acc[r][3]);
      }
    }
    __syncthreads();
  }
#pragma unroll
  for (int r = 0; r < 8; ++r) {
    int row = row0 + rg * 8 + r;
    if (row < n) {
      float dv = dinv[row];
      float4 o;
      o.x = acc[r][0] * dv; o.y = acc[r][1] * dv;
      o.z = acc[r][2] * dv; o.w = acc[r][3] * dv;
      *(float4*)(out + (size_t)row * H + cg) = o;
    }
  }
}

// ---- aggregate (gather): out[i] = maybe_relu(dinv[i]*(sum_{e:dst=i} hs[src] + hs[i]) + b) ----
template <bool RELU>
__global__ __launch_bounds__(256) void aggregate(
    const float* __restrict__ hs, const int* __restrict__ row_start,
    const int* __restrict__ csr_src, const float* __restrict__ dinv,
    const float* __restrict__ b, float* __restrict__ out, int n) {
  int node = blockIdx.x * 8 + (threadIdx.x >> 5);
  if (node >= n) return;
  int c = (threadIdx.x & 31) << 2;
  int beg = row_start[node];
  int end = row_start[node + 1];

  float4 acc = *(const float4*)(hs + (size_t)node * H + c);  // self-loop term
  int k = beg;
  for (; k + 3 < end; k += 4) {
    int s0 = csr_src[k + 0];
    int s1 = csr_src[k + 1];
    int s2 = csr_src[k + 2];
    int s3 = csr_src[k + 3];
    float4 v0 = *(const float4*)(hs + (size_t)s0 * H + c);
    float4 v1 = *(const float4*)(hs + (size_t)s1 * H + c);
    float4 v2 = *(const float4*)(hs + (size_t)s2 * H + c);
    float4 v3 = *(const float4*)(hs + (size_t)s3 * H + c);
    acc.x += (v0.x + v1.x) + (v2.x + v3.x);
    acc.y += (v0.y + v1.y) + (v2.y + v3.y);
    acc.z += (v0.z + v1.z) + (v2.z + v3.z);
    acc.w += (v0.w + v1.w) + (v2.w + v3.w);
  }
  for (; k < end; ++k) {
    int s = csr_src[k];
    float4 v = *(const float4*)(hs + (size_t)s * H + c);
    acc.x += v.x; acc.y += v.y; acc.z += v.z; acc.w += v.w;
  }

  float dv = dinv[node];
  float4 bb = *(const float4*)(b + c);
  float4 o;
  o.x = fmaf(acc.x, dv, bb.x);
  o.y = fmaf(acc.y, dv, bb.y);
  o.z = fmaf(acc.z, dv, bb.z);
  o.w = fmaf(acc.w, dv, bb.w);
  if (RELU) {
    o.x = fmaxf(o.x, 0.f); o.y = fmaxf(o.y, 0.f);
    o.z = fmaxf(o.z, 0.f); o.w = fmaxf(o.w, 0.f);
  }
  *(float4*)(out + (size_t)node * H + c) = o;
}

// ---- segmented pooling: one block per graph; sum+max over contiguous node range ----
__global__ __launch_bounds__(256) void pool2(
    const float* __restrict__ h, const int* __restrict__ g_start,
    float* __restrict__ gmean, float* __restrict__ gmax, int n) {
  __shared__ float ssum[8][H];
  __shared__ float smax[8][H];
  int g = blockIdx.x;
  int beg = g_start[g];
  int end = g_start[g + 1];
  int q = threadIdx.x >> 5;           // group 0..7
  int c = (threadIdx.x & 31) << 2;    // col base

  float4 s = make_float4(0.f, 0.f, 0.f, 0.f);
  float4 m = make_float4(-INFINITY, -INFINITY, -INFINITY, -INFINITY);
  for (int node = beg + q; node < end; node += 8) {
    float4 v = *(const float4*)(h + (size_t)node * H + c);
    s.x += v.x; s.y += v.y; s.z += v.z; s.w += v.w;
    m.x = fmaxf(m.x, v.x); m.y = fmaxf(m.y, v.y);
    m.z = fmaxf(m.z, v.z); m.w = fmaxf(m.w, v.w);
  }
  *(float4*)&ssum[q][c] = s;
  *(float4*)&smax[q][c] = m;
  __syncthreads();

  int cnt = end - beg;
  float inv = 1.0f / fmaxf((float)cnt, 1.0f);
  int t = threadIdx.x;
  if (t < H) {
    float tot = 0.f;
#pragma unroll
    for (int qq = 0; qq < 8; ++qq) tot += ssum[qq][t];
    gmean[(size_t)g * H + t] = tot * inv;
  } else {
    int cc = t - H;
    float mx = -INFINITY;
#pragma unroll
    for (int qq = 0; qq < 8; ++qq) mx = fmaxf(mx, smax[qq][cc]);
    gmax[(size_t)g * H + cc] = (cnt == 0) ? 0.0f : mx;
  }
}

// ---- classifier: one block per graph ----
__global__ __launch_bounds__(128) void classify_kernel(
    const float* __restrict__ gmean, const float* __restrict__ gmax,
    const float* __restrict__ Wc1, const float* __restrict__ bc1,
    const float* __restrict__ Wc2, const float* __restrict__ bc2,
    float* __restrict__ out) {
  __shared__ float gv[2 * H];
  __shared__ float hid[H];
  int gid = blockIdx.x;
  int t = threadIdx.x;
  gv[t] = gmean[(size_t)gid * H + t];
  gv[H + t] = gmax[(size_t)gid * H + t];
  __syncthreads();
  float acc = 0.f;
#pragma unroll 8
  for (int k = 0; k < 2 * H; ++k) acc = fmaf(gv[k], Wc1[(size_t)k * H + t], acc);
  hid[t] = fmaxf(acc + bc1[t], 0.f);
  __syncthreads();
  if (t < 10) {
    float a2 = 0.f;
    for (int j = 0; j < H; ++j) a2 = fmaf(hid[j], Wc2[(size_t)j * 10 + t], a2);
    out[(size_t)gid * 10 + t] = a2 + bc2[t];
  }
}

extern "C" void kernel_launch(void* const* d_in, const int* in_sizes, int n_in,
                              void* d_out, int out_size, void* d_ws, size_t ws_size,
                              hipStream_t stream) {
  const float* x    = (const float*)d_in[0];
  const int* ei     = (const int*)d_in[1];
  const int* batch  = (const int*)d_in[2];
  const float* W1   = (const float*)d_in[3];
  const float* b1   = (const float*)d_in[4];
  const float* W2   = (const float*)d_in[5];
  const float* b2   = (const float*)d_in[6];
  const float* W3   = (const float*)d_in[7];
  const float* b3   = (const float*)d_in[8];
  const float* Wc1  = (const float*)d_in[9];
  const float* bc1  = (const float*)d_in[10];
  const float* Wc2  = (const float*)d_in[11];
  const float* bc2  = (const float*)d_in[12];
  float* out = (float*)d_out;

  const int n  = in_sizes[2];        // 100000 nodes
  const int ne = in_sizes[1] / 2;    // 1600000 edges
  const int G  = 512;
  const size_t NF = (size_t)n * H;

  const int* src = ei;
  const int* dst = ei + ne;

  // ---- workspace layout ----
  float* A = (float*)d_ws;                 // hs buffer  [n,128]
  float* B = A + NF;                       // agg/output [n,128]
  char* p = (char*)(B + NF);
  int*      deg_cnt  = (int*)p;       p += (size_t)n * 4;          // zeroed
  float*    dinv     = (float*)p;     p += (size_t)n * 4;
  int*      row_start= (int*)p;       p += (size_t)(n + 1) * 4;
  int*      cursor   = (int*)p;       p += (size_t)n * 4;
  int*      partials = (int*)p;       p += (size_t)256 * 4;
  int*      g_start  = (int*)p;       p += (size_t)(G + 1) * 4;
  float*    gmean    = (float*)p;     p += (size_t)G * H * 4;
  float*    gmax     = (float*)p;     p += (size_t)G * H * 4;
  int*      csr_src  = (int*)p;       p += (size_t)ne * 4;

  hipMemsetAsync(deg_cnt, 0, (size_t)n * 4, stream);

  // ---- CSR build (once, reused by all 3 layers) ----
  deg_kernel<<<(ne + 255) / 256, 256, 0, stream>>>(dst, deg_cnt, ne);
  dinv_kernel<<<(n + 255) / 256, 256, 0, stream>>>(deg_cnt, dinv, n);
  int nb = (n + 1023) / 1024;
  scan1<<<nb, 256, 0, stream>>>(deg_cnt, row_start, partials, n);
  scan2<<<1, 256, 0, stream>>>(partials, nb);
  scan3<<<(n + 255) / 256, 256, 0, stream>>>(row_start, partials, n, ne);
  hipMemcpyAsync(cursor, row_start, (size_t)n * 4, hipMemcpyDeviceToDevice, stream);
  csr_fill<<<(ne + 255) / 256, 256, 0, stream>>>(src, dst, cursor, csr_src, ne);
  gstart_kernel<<<(n + 255) / 256, 256, 0, stream>>>(batch, g_start, n, G);

  const int gemm_grid = (n + 63) / 64;
  const int node_grid = (n + 7) / 8;

  // ---- layer 1 ----
  gemm_scale<<<gemm_grid, 256, 0, stream>>>(x, W1, dinv, A, n);
  aggregate<true><<<node_grid, 256, 0, stream>>>(A, row_start, csr_src, dinv, b1, B, n);

  // ---- layer 2 ----
  gemm_scale<<<gemm_grid, 256, 0, stream>>>(B, W2, dinv, A, n);
  aggregate<true><<<node_grid, 256, 0, stream>>>(A, row_start, csr_src, dinv, b2, B, n);

  // ---- layer 3 (no relu) ----
  gemm_scale<<<gemm_grid, 256, 0, stream>>>(B, W3, dinv, A, n);
  aggregate<false><<<node_grid, 256, 0, stream>>>(A, row_start, csr_src, dinv, b3, B, n);

  // ---- pooling + classifier ----
  pool2<<<G, 256, 0, stream>>>(B, g_start, gmean, gmax, n);
  classify_kernel<<<G, 128, 0, stream>>>(gmean, gmax, Wc1, bc1, Wc2, bc2, out);
}

// Round 4
// 781.494 us; speedup vs baseline: 11.3705x; 1.0865x over previous
//
#include <hip/hip_runtime.h>

#define H 128

// ---- degree count: cnt[dst[e]] += 1 ----
__global__ void deg_kernel(const int* __restrict__ dst, int* __restrict__ cnt, int ne) {
  int e = blockIdx.x * blockDim.x + threadIdx.x;
  if (e < ne) atomicAdd(&cnt[dst[e]], 1);
}

// ---- dinv[i] = rsqrt(cnt[i] + 1)  (self-loop) ----
__global__ void dinv_kernel(const int* __restrict__ cnt, float* __restrict__ dinv, int n) {
  int i = blockIdx.x * blockDim.x + threadIdx.x;
  if (i < n) dinv[i] = rsqrtf((float)(cnt[i] + 1));
}

// ---- exclusive scan, stage 1: 1024 elems/block ----
__global__ __launch_bounds__(256) void scan1(const int* __restrict__ in,
                                             int* __restrict__ out,
                                             int* __restrict__ partials, int n) {
  __shared__ int sdata[256];
  int base = blockIdx.x * 1024;
  int t = threadIdx.x;
  int v[4];
  int sum = 0;
#pragma unroll
  for (int j = 0; j < 4; ++j) {
    int idx = base + t * 4 + j;
    v[j] = (idx < n) ? in[idx] : 0;
    sum += v[j];
  }
  sdata[t] = sum;
  __syncthreads();
  for (int off = 1; off < 256; off <<= 1) {
    int y = (t >= off) ? sdata[t - off] : 0;
    __syncthreads();
    sdata[t] += y;
    __syncthreads();
  }
  int excl = sdata[t] - sum;
  int run = excl;
#pragma unroll
  for (int j = 0; j < 4; ++j) {
    int idx = base + t * 4 + j;
    if (idx < n) out[idx] = run;
    run += v[j];
  }
  if (t == 255) partials[blockIdx.x] = sdata[255];
}

// ---- scan stage 2: single block scans block totals (nb <= 256) ----
__global__ __launch_bounds__(256) void scan2(int* __restrict__ partials, int nb) {
  __shared__ int sdata[256];
  int t = threadIdx.x;
  int v = (t < nb) ? partials[t] : 0;
  sdata[t] = v;
  __syncthreads();
  for (int off = 1; off < 256; off <<= 1) {
    int y = (t >= off) ? sdata[t - off] : 0;
    __syncthreads();
    sdata[t] += y;
    __syncthreads();
  }
  if (t < nb) partials[t] = sdata[t] - v;
}

// ---- scan stage 3: add block offsets; set row_start[n] = ne ----
__global__ void scan3(int* __restrict__ out, const int* __restrict__ partials,
                      int n, int ne) {
  int i = blockIdx.x * blockDim.x + threadIdx.x;
  if (i < n) out[i] += partials[i >> 10];
  if (i == 0) out[n] = ne;
}

// ---- CSR fill, XCD-partitioned by dst-range for L2 write combining ----
// blockIdx % 8 -> dst range (round-robin XCD heuristic); blockIdx / 8 -> edge slice.
// Correct for ANY block->XCD mapping: the 8 range-groups partition edges exactly.
__global__ __launch_bounds__(256) void csr_fill_x(
    const int* __restrict__ src, const int* __restrict__ dst,
    int* __restrict__ cursor, int* __restrict__ csr_src,
    int ne, int range, int slices) {
  int r = blockIdx.x & 7;
  int slice = blockIdx.x >> 3;
  int chunk = (ne + slices - 1) / slices;
  int beg = slice * chunk;
  int end = beg + chunk; if (end > ne) end = ne;
  int lo = r * range;
  int hi = lo + range;
  for (int e = beg + threadIdx.x; e < end; e += 256) {
    int d = dst[e];
    int s = src[e];
    if (d >= lo && d < hi) {
      int p = atomicAdd(&cursor[d], 1);
      csr_src[p] = s;
    }
  }
}

// ---- graph boundaries from sorted batch ----
__global__ void gstart_kernel(const int* __restrict__ batch, int* __restrict__ g_start,
                              int n, int G) {
  int i = blockIdx.x * blockDim.x + threadIdx.x;
  if (i >= n) return;
  int b = batch[i];
  int prev = (i == 0) ? -1 : batch[i - 1];
  for (int g = prev + 1; g <= b; ++g) g_start[g] = i;
  if (i == n - 1) {
    for (int g = b + 1; g <= G; ++g) g_start[g] = n;
  }
}

// ---- out[r][c] = (X @ W)[r][c] * dinv[r]   (64 rows x 128 cols per block, BK=16) ----
__global__ __launch_bounds__(256) void gemm_scale(
    const float* __restrict__ X, const float* __restrict__ W,
    const float* __restrict__ dinv, float* __restrict__ out, int n) {
  __shared__ float sXT[16][64];   // k-major X tile
  __shared__ float sW[16][H];
  int tid = threadIdx.x;
  int row0 = blockIdx.x * 64;
  int rg = tid >> 5;              // 0..7 -> rows rg*8 .. rg*8+7
  int cg = (tid & 31) << 2;       // col base

  float acc[8][4];
#pragma unroll
  for (int r = 0; r < 8; ++r) { acc[r][0]=0.f; acc[r][1]=0.f; acc[r][2]=0.f; acc[r][3]=0.f; }

  int xrow = tid >> 2;            // 0..63
  int xkq  = (tid & 3) << 2;      // 0,4,8,12
  int wkk  = tid >> 4;            // 0..15
  int wc   = (tid & 15) << 3;     // 0,8,...,120

  for (int k0 = 0; k0 < H; k0 += 16) {
    {
      int r = row0 + xrow;
      float4 v = make_float4(0.f, 0.f, 0.f, 0.f);
      if (r < n) v = *(const float4*)(X + (size_t)r * H + k0 + xkq);
      sXT[xkq + 0][xrow] = v.x;
      sXT[xkq + 1][xrow] = v.y;
      sXT[xkq + 2][xrow] = v.z;
      sXT[xkq + 3][xrow] = v.w;
    }
    {
      const float* wp = W + (size_t)(k0 + wkk) * H + wc;
      *(float4*)&sW[wkk][wc]     = *(const float4*)(wp);
      *(float4*)&sW[wkk][wc + 4] = *(const float4*)(wp + 4);
    }
    __syncthreads();
#pragma unroll
    for (int kk = 0; kk < 16; ++kk) {
      float4 wv = *(float4*)&sW[kk][cg];
      float4 a0 = *(float4*)&sXT[kk][rg * 8];
      float4 a1 = *(float4*)&sXT[kk][rg * 8 + 4];
      acc[0][0] = fmaf(a0.x, wv.x, acc[0][0]); acc[0][1] = fmaf(a0.x, wv.y, acc[0][1]);
      acc[0][2] = fmaf(a0.x, wv.z, acc[0][2]); acc[0][3] = fmaf(a0.x, wv.w, acc[0][3]);
      acc[1][0] = fmaf(a0.y, wv.x, acc[1][0]); acc[1][1] = fmaf(a0.y, wv.y, acc[1][1]);
      acc[1][2] = fmaf(a0.y, wv.z, acc[1][2]); acc[1][3] = fmaf(a0.y, wv.w, acc[1][3]);
      acc[2][0] = fmaf(a0.z, wv.x, acc[2][0]); acc[2][1] = fmaf(a0.z, wv.y, acc[2][1]);
      acc[2][2] = fmaf(a0.z, wv.z, acc[2][2]); acc[2][3] = fmaf(a0.z, wv.w, acc[2][3]);
      acc[3][0] = fmaf(a0.w, wv.x, acc[3][0]); acc[3][1] = fmaf(a0.w, wv.y, acc[3][1]);
      acc[3][2] = fmaf(a0.w, wv.z, acc[3][2]); acc[3][3] = fmaf(a0.w, wv.w, acc[3][3]);
      acc[4][0] = fmaf(a1.x, wv.x, acc[4][0]); acc[4][1] = fmaf(a1.x, wv.y, acc[4][1]);
      acc[4][2] = fmaf(a1.x, wv.z, acc[4][2]); acc[4][3] = fmaf(a1.x, wv.w, acc[4][3]);
      acc[5][0] = fmaf(a1.y, wv.x, acc[5][0]); acc[5][1] = fmaf(a1.y, wv.y, acc[5][1]);
      acc[5][2] = fmaf(a1.y, wv.z, acc[5][2]); acc[5][3] = fmaf(a1.y, wv.w, acc[5][3]);
      acc[6][0] = fmaf(a1.z, wv.x, acc[6][0]); acc[6][1] = fmaf(a1.z, wv.y, acc[6][1]);
      acc[6][2] = fmaf(a1.z, wv.z, acc[6][2]); acc[6][3] = fmaf(a1.z, wv.w, acc[6][3]);
      acc[7][0] = fmaf(a1.w, wv.x, acc[7][0]); acc[7][1] = fmaf(a1.w, wv.y, acc[7][1]);
      acc[7][2] = fmaf(a1.w, wv.z, acc[7][2]); acc[7][3] = fmaf(a1.w, wv.w, acc[7][3]);
    }
    __syncthreads();
  }
#pragma unroll
  for (int r = 0; r < 8; ++r) {
    int row = row0 + rg * 8 + r;
    if (row < n) {
      float dv = dinv[row];
      float4 o;
      o.x = acc[r][0] * dv; o.y = acc[r][1] * dv;
      o.z = acc[r][2] * dv; o.w = acc[r][3] * dv;
      *(float4*)(out + (size_t)row * H + cg) = o;
    }
  }
}

// ---- aggregate (gather): out[i] = maybe_relu(dinv[i]*(sum_{e:dst=i} hs[src] + hs[i]) + b) ----
template <bool RELU>
__global__ __launch_bounds__(256) void aggregate(
    const float* __restrict__ hs, const int* __restrict__ row_start,
    const int* __restrict__ csr_src, const float* __restrict__ dinv,
    const float* __restrict__ b, float* __restrict__ out, int n) {
  int node = blockIdx.x * 8 + (threadIdx.x >> 5);
  if (node >= n) return;
  int c = (threadIdx.x & 31) << 2;
  int beg = row_start[node];
  int end = row_start[node + 1];

  float4 acc = *(const float4*)(hs + (size_t)node * H + c);  // self-loop term
  int k = beg;
  for (; k + 3 < end; k += 4) {
    int s0 = csr_src[k + 0];
    int s1 = csr_src[k + 1];
    int s2 = csr_src[k + 2];
    int s3 = csr_src[k + 3];
    float4 v0 = *(const float4*)(hs + (size_t)s0 * H + c);
    float4 v1 = *(const float4*)(hs + (size_t)s1 * H + c);
    float4 v2 = *(const float4*)(hs + (size_t)s2 * H + c);
    float4 v3 = *(const float4*)(hs + (size_t)s3 * H + c);
    acc.x += (v0.x + v1.x) + (v2.x + v3.x);
    acc.y += (v0.y + v1.y) + (v2.y + v3.y);
    acc.z += (v0.z + v1.z) + (v2.z + v3.z);
    acc.w += (v0.w + v1.w) + (v2.w + v3.w);
  }
  for (; k < end; ++k) {
    int s = csr_src[k];
    float4 v = *(const float4*)(hs + (size_t)s * H + c);
    acc.x += v.x; acc.y += v.y; acc.z += v.z; acc.w += v.w;
  }

  float dv = dinv[node];
  float4 bb = *(const float4*)(b + c);
  float4 o;
  o.x = fmaf(acc.x, dv, bb.x);
  o.y = fmaf(acc.y, dv, bb.y);
  o.z = fmaf(acc.z, dv, bb.z);
  o.w = fmaf(acc.w, dv, bb.w);
  if (RELU) {
    o.x = fmaxf(o.x, 0.f); o.y = fmaxf(o.y, 0.f);
    o.z = fmaxf(o.z, 0.f); o.w = fmaxf(o.w, 0.f);
  }
  *(float4*)(out + (size_t)node * H + c) = o;
}

// ---- segmented pooling: one block per graph ----
__global__ __launch_bounds__(256) void pool2(
    const float* __restrict__ h, const int* __restrict__ g_start,
    float* __restrict__ gmean, float* __restrict__ gmax, int n) {
  __shared__ float ssum[8][H];
  __shared__ float smax[8][H];
  int g = blockIdx.x;
  int beg = g_start[g];
  int end = g_start[g + 1];
  int q = threadIdx.x >> 5;
  int c = (threadIdx.x & 31) << 2;

  float4 s = make_float4(0.f, 0.f, 0.f, 0.f);
  float4 m = make_float4(-INFINITY, -INFINITY, -INFINITY, -INFINITY);
  for (int node = beg + q; node < end; node += 8) {
    float4 v = *(const float4*)(h + (size_t)node * H + c);
    s.x += v.x; s.y += v.y; s.z += v.z; s.w += v.w;
    m.x = fmaxf(m.x, v.x); m.y = fmaxf(m.y, v.y);
    m.z = fmaxf(m.z, v.z); m.w = fmaxf(m.w, v.w);
  }
  *(float4*)&ssum[q][c] = s;
  *(float4*)&smax[q][c] = m;
  __syncthreads();

  int cnt = end - beg;
  float inv = 1.0f / fmaxf((float)cnt, 1.0f);
  int t = threadIdx.x;
  if (t < H) {
    float tot = 0.f;
#pragma unroll
    for (int qq = 0; qq < 8; ++qq) tot += ssum[qq][t];
    gmean[(size_t)g * H + t] = tot * inv;
  } else {
    int cc = t - H;
    float mx = -INFINITY;
#pragma unroll
    for (int qq = 0; qq < 8; ++qq) mx = fmaxf(mx, smax[qq][cc]);
    gmax[(size_t)g * H + cc] = (cnt == 0) ? 0.0f : mx;
  }
}

// ---- classifier: one block per graph ----
__global__ __launch_bounds__(128) void classify_kernel(
    const float* __restrict__ gmean, const float* __restrict__ gmax,
    const float* __restrict__ Wc1, const float* __restrict__ bc1,
    const float* __restrict__ Wc2, const float* __restrict__ bc2,
    float* __restrict__ out) {
  __shared__ float gv[2 * H];
  __shared__ float hid[H];
  int gid = blockIdx.x;
  int t = threadIdx.x;
  gv[t] = gmean[(size_t)gid * H + t];
  gv[H + t] = gmax[(size_t)gid * H + t];
  __syncthreads();
  float acc = 0.f;
#pragma unroll 8
  for (int k = 0; k < 2 * H; ++k) acc = fmaf(gv[k], Wc1[(size_t)k * H + t], acc);
  hid[t] = fmaxf(acc + bc1[t], 0.f);
  __syncthreads();
  if (t < 10) {
    float a2 = 0.f;
    for (int j = 0; j < H; ++j) a2 = fmaf(hid[j], Wc2[(size_t)j * 10 + t], a2);
    out[(size_t)gid * 10 + t] = a2 + bc2[t];
  }
}

extern "C" void kernel_launch(void* const* d_in, const int* in_sizes, int n_in,
                              void* d_out, int out_size, void* d_ws, size_t ws_size,
                              hipStream_t stream) {
  const float* x    = (const float*)d_in[0];
  const int* ei     = (const int*)d_in[1];
  const int* batch  = (const int*)d_in[2];
  const float* W1   = (const float*)d_in[3];
  const float* b1   = (const float*)d_in[4];
  const float* W2   = (const float*)d_in[5];
  const float* b2   = (const float*)d_in[6];
  const float* W3   = (const float*)d_in[7];
  const float* b3   = (const float*)d_in[8];
  const float* Wc1  = (const float*)d_in[9];
  const float* bc1  = (const float*)d_in[10];
  const float* Wc2  = (const float*)d_in[11];
  const float* bc2  = (const float*)d_in[12];
  float* out = (float*)d_out;

  const int n  = in_sizes[2];        // 100000 nodes
  const int ne = in_sizes[1] / 2;    // 1600000 edges
  const int G  = 512;
  const size_t NF = (size_t)n * H;

  const int* src = ei;
  const int* dst = ei + ne;

  // ---- workspace layout ----
  float* A = (float*)d_ws;
  float* B = A + NF;
  char* p = (char*)(B + NF);
  int*      deg_cnt  = (int*)p;       p += (size_t)n * 4;
  float*    dinv     = (float*)p;     p += (size_t)n * 4;
  int*      row_start= (int*)p;       p += (size_t)(n + 1) * 4;
  int*      cursor   = (int*)p;       p += (size_t)n * 4;
  int*      partials = (int*)p;       p += (size_t)256 * 4;
  int*      g_start  = (int*)p;       p += (size_t)(G + 1) * 4;
  float*    gmean    = (float*)p;     p += (size_t)G * H * 4;
  float*    gmax     = (float*)p;     p += (size_t)G * H * 4;
  int*      csr_src  = (int*)p;       p += (size_t)ne * 4;

  hipMemsetAsync(deg_cnt, 0, (size_t)n * 4, stream);

  // ---- CSR build (once, reused by all 3 layers) ----
  deg_kernel<<<(ne + 255) / 256, 256, 0, stream>>>(dst, deg_cnt, ne);
  dinv_kernel<<<(n + 255) / 256, 256, 0, stream>>>(deg_cnt, dinv, n);
  int nb = (n + 1023) / 1024;
  scan1<<<nb, 256, 0, stream>>>(deg_cnt, row_start, partials, n);
  scan2<<<1, 256, 0, stream>>>(partials, nb);
  scan3<<<(n + 255) / 256, 256, 0, stream>>>(row_start, partials, n, ne);
  hipMemcpyAsync(cursor, row_start, (size_t)n * 4, hipMemcpyDeviceToDevice, stream);
  {
    int range = (n + 7) / 8;
    int slices = 128;
    csr_fill_x<<<slices * 8, 256, 0, stream>>>(src, dst, cursor, csr_src, ne, range, slices);
  }
  gstart_kernel<<<(n + 255) / 256, 256, 0, stream>>>(batch, g_start, n, G);

  const int gemm_grid = (n + 63) / 64;
  const int node_grid = (n + 7) / 8;

  // ---- layer 1 ----
  gemm_scale<<<gemm_grid, 256, 0, stream>>>(x, W1, dinv, A, n);
  aggregate<true><<<node_grid, 256, 0, stream>>>(A, row_start, csr_src, dinv, b1, B, n);

  // ---- layer 2 ----
  gemm_scale<<<gemm_grid, 256, 0, stream>>>(B, W2, dinv, A, n);
  aggregate<true><<<node_grid, 256, 0, stream>>>(A, row_start, csr_src, dinv, b2, B, n);

  // ---- layer 3 (no relu) ----
  gemm_scale<<<gemm_grid, 256, 0, stream>>>(B, W3, dinv, A, n);
  aggregate<false><<<node_grid, 256, 0, stream>>>(A, row_start, csr_src, dinv, b3, B, n);

  // ---- pooling + classifier ----
  pool2<<<G, 256, 0, stream>>>(B, g_start, gmean, gmax, n);
  classify_kernel<<<G, 128, 0, stream>>>(gmean, gmax, Wc1, bc1, Wc2, bc2, out);
}